// Round 5
// baseline (627.008 us; speedup 1.0000x reference)
//
#include <hip/hip_runtime.h>
#include <math.h>

// Problem constants: B=2, H=W=32 (after expand), L=1024, out_dim=384, Di=768,
// K=4 directions, N=16 state, R=24, depth=2. fp32 in/out; bf16 MFMA GEMMs.

typedef __attribute__((ext_vector_type(8))) short s8v;   // 8 bf16 = 4 VGPRs
typedef __attribute__((ext_vector_type(4))) float f4v;

static __device__ __forceinline__ float sigmoidf_(float x) {
    return 1.f / (1.f + __expf(-x));
}
static __device__ __forceinline__ ushort f2bf(float x) {
    unsigned u = __float_as_uint(x);
    return (ushort)((u + 0x7fff + ((u >> 16) & 1)) >> 16);   // RNE
}
static __device__ __forceinline__ float bf2f(ushort u) {
    return __uint_as_float(((unsigned)u) << 16);
}

// Scan-order <-> spatial-position map. Involution for all k.
static __device__ __forceinline__ int scan_pos(int k, int l) {
    int m = (k & 2) ? (1023 - l) : l;
    return (k & 1) ? (((m & 31) << 5) | (m >> 5)) : m;
}

// ---------------- all weight conversions fp32->bf16 in ONE kernel ----------------
__global__ __launch_bounds__(256) void cvt_all_k(
    const float* __restrict__ pew, const float* __restrict__ lpw,
    const float* __restrict__ inw, const float* __restrict__ ow,
    const float* __restrict__ xpw, const float* __restrict__ dtw,
    ushort* __restrict__ wpe, ushort* __restrict__ wlp,
    ushort* __restrict__ winb, ushort* __restrict__ wob,
    ushort* __restrict__ wxpp, ushort* __restrict__ wdtp) {
    int g = blockIdx.x * 256 + threadIdx.x;
    if (g < 811008) {
        const float* s; ushort* d; int off;
        if (g < 294912)      { s = pew;  d = wpe;  off = g; }
        else if (g < 368640) { s = lpw;  d = wlp;  off = g - 294912; }
        else if (g < 663552) { s = inw;  d = winb; off = g - 368640; }
        else                 { s = ow;   d = wob;  off = g - 663552; }
        float4 v = ((const float4*)s)[off];
        ushort4 o = {f2bf(v.x), f2bf(v.y), f2bf(v.z), f2bf(v.w)};
        ((ushort4*)d)[off] = o;
    } else if (g < 909312) {
        int e = g - 811008;
        int blkb = e / 49152, rem = e % 49152;
        int n = rem / 192, q = rem % 192;
        int k = n >> 6, c = n & 63;
        ushort4 o = {0, 0, 0, 0};
        if (c < 56) {
            float4 v = *(const float4*)(xpw +
                ((size_t)((blkb * 4 + k) * 56 + c)) * 768 + q * 4);
            o = {f2bf(v.x), f2bf(v.y), f2bf(v.z), f2bf(v.w)};
        }
        ((ushort4*)wxpp)[e] = o;
    } else {
        int e = g - 909312;          // 49152 groups
        int rowk = e >> 3, q = e & 7;
        ushort4 o = {0, 0, 0, 0};
        if (q < 6) {
            float4 v = *(const float4*)(dtw + (size_t)rowk * 24 + q * 4);
            o = {f2bf(v.x), f2bf(v.y), f2bf(v.z), f2bf(v.w)};
        }
        ((ushort4*)wdtp)[e] = o;
    }
}

// ---------------- tiled transpose: x (B,768,256) -> (B*256,768) bf16 -------------
__global__ __launch_bounds__(256) void tr_x_k(const float* __restrict__ x,
                                              ushort* __restrict__ o) {
    __shared__ float tile[32][33];
    int b = blockIdx.z, c0 = blockIdx.y * 32, s0 = blockIdx.x * 32;
    int tx = threadIdx.x & 31, ty = threadIdx.x >> 5;
    for (int i = ty; i < 32; i += 8)
        tile[i][tx] = x[((size_t)(b * 768 + c0 + i)) * 256 + s0 + tx];
    __syncthreads();
    for (int i = ty; i < 32; i += 8)
        o[((size_t)(b * 256 + s0 + i)) * 768 + c0 + tx] = f2bf(tile[tx][i]);
}

// ---------------- merged: pe_ln (blocks 0..511) + tr_skip (blocks 512..1279) -----
__global__ __launch_bounds__(256) void peskip_k(const float* __restrict__ t1,
                                                const float* __restrict__ pnw,
                                                const float* __restrict__ pnb,
                                                const float* __restrict__ skip,
                                                ushort* __restrict__ cin) {
    __shared__ float tile[32][33];
    int bx = blockIdx.x;
    if (bx < 512) {
        // pixel-shuffle + LN -> cin cols [0,384), wave per row
        int w = threadIdx.x >> 6, lane = threadIdx.x & 63;
        int row = bx * 4 + w;
        int b = row >> 10, p = row & 1023;
        int r = p >> 5, col = p & 31;
        int i = r >> 1, a = r & 1, j = col >> 1, b2 = col & 1;
        const float* src =
            t1 + ((size_t)(b * 256 + i * 16 + j)) * 1536 + (a * 2 + b2) * 384;
        float v[6], s1 = 0.f, s2 = 0.f;
#pragma unroll
        for (int q = 0; q < 6; ++q) {
            v[q] = src[lane + 64 * q];
            s1 += v[q]; s2 += v[q] * v[q];
        }
#pragma unroll
        for (int m = 1; m < 64; m <<= 1) {
            s1 += __shfl_xor(s1, m); s2 += __shfl_xor(s2, m);
        }
        float mean = s1 * (1.f / 384.f);
        float rstd = rsqrtf(s2 * (1.f / 384.f) - mean * mean + 1e-5f);
        ushort* o = cin + (size_t)row * 768;
#pragma unroll
        for (int q = 0; q < 6; ++q) {
            int c = lane + 64 * q;
            o[c] = f2bf((v[q] - mean) * rstd * pnw[c] + pnb[c]);
        }
    } else {
        // skip (B,384,1024) transpose -> cin cols [384,768)
        int idx = bx - 512;                 // 768 blocks: b (2) x c0 (12) x s0 (32)
        int b = idx / 384, rem = idx % 384;
        int c0 = (rem / 32) * 32, s0 = (rem % 32) * 32;
        int tx = threadIdx.x & 31, ty = threadIdx.x >> 5;
        for (int i = ty; i < 32; i += 8)
            tile[i][tx] = skip[((size_t)(b * 384 + c0 + i)) * 1024 + s0 + tx];
        __syncthreads();
        for (int i = ty; i < 32; i += 8)
            cin[((size_t)(b * 1024 + s0 + i)) * 768 + 384 + c0 + tx] =
                f2bf(tile[tx][i]);
    }
}

// ---------------- tiled transpose: xh (B*1024,384) -> out (B,384,1024) fp32 ------
__global__ __launch_bounds__(256) void tr_out_k(const float* __restrict__ xh,
                                                float* __restrict__ out) {
    __shared__ float tile[32][33];
    int b = blockIdx.z, p0 = blockIdx.x * 32, c0 = blockIdx.y * 32;
    int tx = threadIdx.x & 31, ty = threadIdx.x >> 5;
    for (int i = ty; i < 32; i += 8)
        tile[i][tx] = xh[((size_t)(b * 1024 + p0 + i)) * 384 + c0 + tx];
    __syncthreads();
    for (int i = ty; i < 32; i += 8)
        out[((size_t)(b * 384 + c0 + i)) * 1024 + p0 + tx] = tile[tx][i];
}

// ---------------- bf16 NT MFMA GEMM, z-batched, 3 epilogue modes -----------------
// mode 0: Cf = acc (+bias)(+res)  fp32
// mode 1: Cb = bf16(softplus(acc + bias))          [z-batched]
// mode 2: xproj scatter: dtrb bf16 (c<32, zero-pad 24..31), dblBC fp32 scan-order
__global__ __launch_bounds__(256) void gemm_bf(const ushort* __restrict__ A,
                                               const ushort* __restrict__ B,
                                               const float* __restrict__ bias,
                                               const float* __restrict__ res,
                                               float* __restrict__ Cf,
                                               ushort* __restrict__ Cb,
                                               float* __restrict__ dblBC,
                                               ushort* __restrict__ dtrb,
                                               int M, int N, int K,
                                               long sAz, long sBz, long sBiz,
                                               long sCz, int mode) {
    __shared__ ushort Als[128][40];   // 80 B rows: 20-bank stride, worst 2-way
    __shared__ ushort Bls[128][40];
    A += (size_t)blockIdx.z * sAz;
    B += (size_t)blockIdx.z * sBz;
    if (Cf) Cf += (size_t)blockIdx.z * sCz;
    if (Cb) Cb += (size_t)blockIdx.z * sCz;
    if (bias) bias += (size_t)blockIdx.z * sBiz;
    int t = threadIdx.x;
    int bm = blockIdx.y * 128, bn = blockIdx.x * 128;
    int lane = t & 63, w = t >> 6;
    int wm = (w & 1) * 64, wn = (w >> 1) * 64;
    int r16 = lane & 15, quad = lane >> 4;
    int srow = t >> 1, shalf = t & 1;
    f4v acc[4][4] = {};
    const ushort* Ag = A + (size_t)(bm + srow) * K + shalf * 16;
    const ushort* Bg = B + (size_t)(bn + srow) * K + shalf * 16;
    for (int k0 = 0; k0 < K; k0 += 32) {
        uint4 a0 = *(const uint4*)(Ag + k0);
        uint4 a1 = *(const uint4*)(Ag + k0 + 8);
        uint4 b0 = *(const uint4*)(Bg + k0);
        uint4 b1 = *(const uint4*)(Bg + k0 + 8);
        __syncthreads();
        *(uint4*)&Als[srow][shalf * 16] = a0;
        *(uint4*)&Als[srow][shalf * 16 + 8] = a1;
        *(uint4*)&Bls[srow][shalf * 16] = b0;
        *(uint4*)&Bls[srow][shalf * 16 + 8] = b1;
        __syncthreads();
        s8v af[4], bfr[4];
#pragma unroll
        for (int i = 0; i < 4; ++i) {
            af[i]  = *(const s8v*)&Als[wm + i * 16 + r16][quad * 8];
            bfr[i] = *(const s8v*)&Bls[wn + i * 16 + r16][quad * 8];
        }
#pragma unroll
        for (int i = 0; i < 4; ++i)
#pragma unroll
            for (int j = 0; j < 4; ++j)
                acc[i][j] = __builtin_amdgcn_mfma_f32_16x16x32_bf16(
                    af[i], bfr[j], acc[i][j], 0, 0, 0);
    }
    // D mapping: col=lane&15, row=quad*4+reg (m89-verified)
#pragma unroll
    for (int i = 0; i < 4; ++i) {
        int row0 = bm + wm + i * 16 + quad * 4;
#pragma unroll
        for (int j = 0; j < 4; ++j) {
            int col = bn + wn + j * 16 + r16;
            float bv = bias ? bias[col] : 0.f;
#pragma unroll
            for (int r = 0; r < 4; ++r) {
                int row = row0 + r;
                float v = acc[i][j][r] + bv;
                if (mode == 0) {
                    if (res) v += res[(size_t)row * N + col];
                    Cf[(size_t)row * N + col] = v;
                } else if (mode == 1) {
                    v = (v > 20.f) ? v : log1pf(__expf(v));
                    Cb[(size_t)row * N + col] = f2bf(v);
                } else {
                    int k = col >> 6, c = col & 63;
                    int b = row >> 10, p = row & 1023;
                    if (c < 32)
                        dtrb[((size_t)k * 2048 + row) * 32 + c] =
                            f2bf((c < 24) ? v : 0.f);
                    if (c >= 24 && c < 56) {
                        int l = scan_pos(k, p);
                        dblBC[(((size_t)(b * 4 + k)) * 1024 + l) * 32 + (c - 24)] = v;
                    }
                }
            }
        }
    }
}

// ---------------- row LayerNorm over 384 cols -> bf16 (wave/row) ----------------
__global__ __launch_bounds__(256) void ln_rows_384(const float* __restrict__ in,
                                                   const float* __restrict__ wgt,
                                                   const float* __restrict__ bb,
                                                   ushort* __restrict__ out) {
    int w = threadIdx.x >> 6, lane = threadIdx.x & 63;
    int row = blockIdx.x * 4 + w;      // grid 512
    const float* x = in + (size_t)row * 384;
    float v[6], s1 = 0.f, s2 = 0.f;
#pragma unroll
    for (int q = 0; q < 6; ++q) {
        v[q] = x[lane + 64 * q];
        s1 += v[q]; s2 += v[q] * v[q];
    }
#pragma unroll
    for (int m = 1; m < 64; m <<= 1) {
        s1 += __shfl_xor(s1, m); s2 += __shfl_xor(s2, m);
    }
    float mean = s1 * (1.f / 384.f);
    float rstd = rsqrtf(s2 * (1.f / 384.f) - mean * mean + 1e-5f);
#pragma unroll
    for (int q = 0; q < 6; ++q) {
        int c = lane + 64 * q;
        out[(size_t)row * 384 + c] = f2bf((v[q] - mean) * rstd * wgt[c] + bb[c]);
    }
}

// ---------------- depthwise 3x3 conv + bias + SiLU -> xcb bf16 only --------------
__global__ __launch_bounds__(256) void conv_silu_k(const float* __restrict__ xz,
                                                   const float* __restrict__ cw,
                                                   const float* __restrict__ cb,
                                                   ushort* __restrict__ xcb) {
    int row = blockIdx.x;
    int b = row >> 10, p = row & 1023;
    int r = p >> 5, col = p & 31;
    for (int d = threadIdx.x; d < 768; d += 256) {
        float acc = cb[d];
#pragma unroll
        for (int dy = 0; dy < 3; ++dy) {
            int rr = r + dy - 1;
            if ((unsigned)rr > 31u) continue;
#pragma unroll
            for (int dx = 0; dx < 3; ++dx) {
                int cc = col + dx - 1;
                if ((unsigned)cc > 31u) continue;
                acc += cw[d * 9 + dy * 3 + dx] *
                       xz[((size_t)(b * 1024 + rr * 32 + cc)) * 1536 + d];
            }
        }
        float o = acc * sigmoidf_(acc);
        xcb[(size_t)row * 768 + d] = f2bf(o);
    }
}

// ======== selective scan: p1 (chunk P,H) -> comb (prefix h0) -> p2 (emit) ========
// dtspb bf16 [k][b*1024+p][768]; xcb bf16 [b*1024+p][768]; dblBC fp32 scan-order.
// Pg/Hg/H0g layout: [(kb*16+ch)*12288 + d*16 + n].

__global__ __launch_bounds__(64) void scan_p1(const ushort* __restrict__ dtspb,
                                              const float* __restrict__ dblBC,
                                              const ushort* __restrict__ xcb,
                                              const float* __restrict__ alog,
                                              float* __restrict__ Pg,
                                              float* __restrict__ Hg) {
    __shared__ float sB[32][16];
    int lane = threadIdx.x;
    int d0 = blockIdx.x * 64, ch = blockIdx.y, kb = blockIdx.z;
    int k = kb & 3, b = kb >> 2;
    int d = d0 + lane;
    float A2[16];
    {
        const float4* ap = (const float4*)(alog + ((size_t)(k * 768 + d)) * 16);
#pragma unroll
        for (int q = 0; q < 4; ++q) {
            float4 v = ap[q];
            A2[4 * q + 0] = -__expf(v.x) * 1.44269504f;
            A2[4 * q + 1] = -__expf(v.y) * 1.44269504f;
            A2[4 * q + 2] = -__expf(v.z) * 1.44269504f;
            A2[4 * q + 3] = -__expf(v.w) * 1.44269504f;
        }
    }
    const ushort* dts = dtspb + ((size_t)(k * 2048 + b * 1024)) * 768 + d;
    const ushort* xub = xcb + (size_t)b * 786432 + d;
    const float* bcp = dblBC + (size_t)kb * 1024 * 32;
    int l0 = ch * 64;
    float h[16], P[16];
#pragma unroll
    for (int n = 0; n < 16; ++n) { h[n] = 0.f; P[n] = 1.f; }
    int bi = lane >> 4, bn_ = lane & 15;
#pragma unroll 1
    for (int w = 0; w < 2; ++w) {
        int lw = l0 + w * 32;
        float rdt[32], ru[32], rB[8];
#pragma unroll
        for (int i = 0; i < 32; ++i) {
            int p = scan_pos(k, lw + i);
            rdt[i] = bf2f(dts[(size_t)p * 768]);
            ru[i] = bf2f(xub[(size_t)p * 768]);
        }
#pragma unroll
        for (int j = 0; j < 8; ++j)
            rB[j] = bcp[(size_t)(lw + bi + 4 * j) * 32 + bn_];
        __syncthreads();
#pragma unroll
        for (int j = 0; j < 8; ++j) sB[bi + 4 * j][bn_] = rB[j];
        __syncthreads();
#pragma unroll 4
        for (int i = 0; i < 32; ++i) {
            float dtv = rdt[i], dtu = dtv * ru[i];
            const float4* B4 = (const float4*)&sB[i][0];
            float4 q0 = B4[0], q1 = B4[1], q2 = B4[2], q3 = B4[3];
            float Bv[16] = {q0.x, q0.y, q0.z, q0.w, q1.x, q1.y, q1.z, q1.w,
                            q2.x, q2.y, q2.z, q2.w, q3.x, q3.y, q3.z, q3.w};
#pragma unroll
            for (int n = 0; n < 16; ++n) {
                float a = __builtin_amdgcn_exp2f(dtv * A2[n]);
                P[n] *= a;
                h[n] = a * h[n] + dtu * Bv[n];
            }
        }
    }
    float* pp = Pg + ((size_t)(kb * 16 + ch)) * 12288 + d * 16;
    float* hp = Hg + ((size_t)(kb * 16 + ch)) * 12288 + d * 16;
#pragma unroll
    for (int q = 0; q < 4; ++q) {
        float4 pv = {P[4 * q], P[4 * q + 1], P[4 * q + 2], P[4 * q + 3]};
        float4 hv = {h[4 * q], h[4 * q + 1], h[4 * q + 2], h[4 * q + 3]};
        *(float4*)(pp + 4 * q) = pv;
        *(float4*)(hp + 4 * q) = hv;
    }
}

// prefix fold: h0[ch] for all chains. grid 384 x 256 threads, fully unrolled.
__global__ __launch_bounds__(256) void comb_k(const float* __restrict__ Pg,
                                              const float* __restrict__ Hg,
                                              float* __restrict__ H0g) {
    int t = blockIdx.x * 256 + threadIdx.x;   // 98304 = 8 kb * 12288 (d*16+n)
    int kb = t / 12288, dn = t % 12288;
    size_t base = (size_t)kb * 16 * 12288 + dn;
    float pv[15], hv[15];
#pragma unroll
    for (int ch = 0; ch < 15; ++ch) {
        pv[ch] = Pg[base + (size_t)ch * 12288];
        hv[ch] = Hg[base + (size_t)ch * 12288];
    }
    float h = 0.f;
    H0g[base] = 0.f;
#pragma unroll
    for (int ch = 0; ch < 15; ++ch) {
        h = pv[ch] * h + hv[ch];
        H0g[base + (size_t)(ch + 1) * 12288] = h;
    }
}

__global__ __launch_bounds__(64) void scan_p2(const ushort* __restrict__ dtspb,
                                              const float* __restrict__ dblBC,
                                              const ushort* __restrict__ xcb,
                                              const float* __restrict__ alog,
                                              const float* __restrict__ H0g,
                                              ushort* __restrict__ y4b) {
    __shared__ float sB[32][16];
    __shared__ float sC[32][16];
    int lane = threadIdx.x;
    int d0 = blockIdx.x * 64, ch = blockIdx.y, kb = blockIdx.z;
    int k = kb & 3, b = kb >> 2;
    int d = d0 + lane;
    float A2[16];
    {
        const float4* ap = (const float4*)(alog + ((size_t)(k * 768 + d)) * 16);
#pragma unroll
        for (int q = 0; q < 4; ++q) {
            float4 v = ap[q];
            A2[4 * q + 0] = -__expf(v.x) * 1.44269504f;
            A2[4 * q + 1] = -__expf(v.y) * 1.44269504f;
            A2[4 * q + 2] = -__expf(v.z) * 1.44269504f;
            A2[4 * q + 3] = -__expf(v.w) * 1.44269504f;
        }
    }
    float h[16];
    {
        const float4* h0p =
            (const float4*)(H0g + ((size_t)(kb * 16 + ch)) * 12288 + d * 16);
#pragma unroll
        for (int q = 0; q < 4; ++q) {
            float4 hv = h0p[q];
            h[4 * q + 0] = hv.x; h[4 * q + 1] = hv.y;
            h[4 * q + 2] = hv.z; h[4 * q + 3] = hv.w;
        }
    }
    const ushort* dts = dtspb + ((size_t)(k * 2048 + b * 1024)) * 768 + d;
    const ushort* xub = xcb + (size_t)b * 786432 + d;
    const float* bcp = dblBC + (size_t)kb * 1024 * 32;
    ushort* yp = y4b + (size_t)kb * 786432 + d;
    int l0 = ch * 64;
    int bi = lane >> 4, bn_ = lane & 15;
#pragma unroll 1
    for (int w = 0; w < 2; ++w) {
        int lw = l0 + w * 32;
        float rdt[32], ru[32], rB[8], rC[8];
#pragma unroll
        for (int i = 0; i < 32; ++i) {
            int p = scan_pos(k, lw + i);
            rdt[i] = bf2f(dts[(size_t)p * 768]);
            ru[i] = bf2f(xub[(size_t)p * 768]);
        }
#pragma unroll
        for (int j = 0; j < 8; ++j) {
            rB[j] = bcp[(size_t)(lw + bi + 4 * j) * 32 + bn_];
            rC[j] = bcp[(size_t)(lw + bi + 4 * j) * 32 + 16 + bn_];
        }
        __syncthreads();
#pragma unroll
        for (int j = 0; j < 8; ++j) {
            sB[bi + 4 * j][bn_] = rB[j];
            sC[bi + 4 * j][bn_] = rC[j];
        }
        __syncthreads();
#pragma unroll 4
        for (int i = 0; i < 32; ++i) {
            float dtv = rdt[i], dtu = dtv * ru[i];
            const float4* B4 = (const float4*)&sB[i][0];
            const float4* C4 = (const float4*)&sC[i][0];
            float4 q0 = B4[0], q1 = B4[1], q2 = B4[2], q3 = B4[3];
            float Bv[16] = {q0.x, q0.y, q0.z, q0.w, q1.x, q1.y, q1.z, q1.w,
                            q2.x, q2.y, q2.z, q2.w, q3.x, q3.y, q3.z, q3.w};
            float4 c0 = C4[0], c1 = C4[1], c2 = C4[2], c3 = C4[3];
            float Cv[16] = {c0.x, c0.y, c0.z, c0.w, c1.x, c1.y, c1.z, c1.w,
                            c2.x, c2.y, c2.z, c2.w, c3.x, c3.y, c3.z, c3.w};
            float y = 0.f;
#pragma unroll
            for (int n = 0; n < 16; ++n) {
                float a = __builtin_amdgcn_exp2f(dtv * A2[n]);
                h[n] = a * h[n] + dtu * Bv[n];
                y += h[n] * Cv[n];
            }
            int p = scan_pos(k, lw + i);
            yp[(size_t)p * 768] = f2bf(y);
        }
    }
}

// ---------------- sum 4 dirs + D*u, out-LN, * silu(z) -> g bf16 (wave/row) -------
__global__ __launch_bounds__(256) void fuse_out_k(const ushort* __restrict__ y4b,
                                                  const ushort* __restrict__ xcb,
                                                  const float* __restrict__ xz,
                                                  const float* __restrict__ ds,
                                                  const float* __restrict__ onw,
                                                  const float* __restrict__ onb,
                                                  ushort* __restrict__ g) {
    int w = threadIdx.x >> 6, lane = threadIdx.x & 63;
    int row = blockIdx.x * 4 + w;      // grid 512
    int b = row >> 10, p = row & 1023;
    float v[12], s1 = 0.f, s2 = 0.f;
#pragma unroll
    for (int q = 0; q < 12; ++q) {
        int d = lane + 64 * q;
        float u = bf2f(xcb[(size_t)row * 768 + d]);
        float dsum = ds[d] + ds[768 + d] + ds[1536 + d] + ds[2304 + d];
        float val = dsum * u;
#pragma unroll
        for (int k = 0; k < 4; ++k)
            val += bf2f(y4b[(((size_t)(b * 4 + k)) * 1024 + p) * 768 + d]);
        v[q] = val; s1 += val; s2 += val * val;
    }
#pragma unroll
    for (int m = 1; m < 64; m <<= 1) {
        s1 += __shfl_xor(s1, m); s2 += __shfl_xor(s2, m);
    }
    float mean = s1 * (1.f / 768.f);
    float rstd = rsqrtf(s2 * (1.f / 768.f) - mean * mean + 1e-5f);
#pragma unroll
    for (int q = 0; q < 12; ++q) {
        int d = lane + 64 * q;
        float zz = xz[(size_t)row * 1536 + 768 + d];
        float sil = zz * sigmoidf_(zz);
        g[(size_t)row * 768 + d] = f2bf(((v[q] - mean) * rstd * onw[d] + onb[d]) * sil);
    }
}

extern "C" void kernel_launch(void* const* d_in, const int* in_sizes, int n_in,
                              void* d_out, int out_size, void* d_ws, size_t ws_size,
                              hipStream_t stream) {
    const float* x    = (const float*)d_in[0];
    const float* skip = (const float*)d_in[1];
    const float* pew  = (const float*)d_in[2];
    const float* pnw  = (const float*)d_in[3];
    const float* pnb  = (const float*)d_in[4];
    const float* lpw  = (const float*)d_in[5];
    const float* lpb  = (const float*)d_in[6];
    const float* blw  = (const float*)d_in[7];
    const float* blb  = (const float*)d_in[8];
    const float* inw  = (const float*)d_in[9];
    const float* cw   = (const float*)d_in[10];
    const float* cb   = (const float*)d_in[11];
    const float* xpw  = (const float*)d_in[12];
    const float* dtw  = (const float*)d_in[13];
    const float* dtbi = (const float*)d_in[14];
    const float* alog = (const float*)d_in[15];
    const float* ds   = (const float*)d_in[16];
    const float* onw  = (const float*)d_in[17];
    const float* onb  = (const float*)d_in[18];
    const float* ow   = (const float*)d_in[19];
    float* out = (float*)d_out;

    char* base = (char*)d_ws;
    auto alloc = [&](size_t bytes) -> char* {
        char* p = base;
        base += (bytes + 255) & ~(size_t)255;
        return p;
    };
    float*  xh    = (float*)alloc(2048 * 384 * 4);
    ushort* hbuf  = (ushort*)alloc(2048 * 768 * 2);
    float*  xz    = (float*)alloc((size_t)2048 * 1536 * 4);
    ushort* xcb   = (ushort*)alloc(2048 * 768 * 2);
    float*  dblBC = (float*)alloc(8192 * 32 * 4);
    ushort* dtrb  = (ushort*)alloc((size_t)4 * 2048 * 32 * 2);
    ushort* dtspb = (ushort*)alloc((size_t)4 * 2048 * 768 * 2);
    ushort* y4b   = (ushort*)alloc((size_t)8192 * 768 * 2);
    float*  Pg    = (float*)alloc((size_t)8 * 16 * 12288 * 4);
    float*  Hg    = (float*)alloc((size_t)8 * 16 * 12288 * 4);
    float*  H0g   = (float*)alloc((size_t)8 * 16 * 12288 * 4);
    ushort* xspe  = (ushort*)alloc(512 * 768 * 2);
    float*  t1    = (float*)alloc(512 * 1536 * 4);
    ushort* wpe   = (ushort*)alloc((size_t)1536 * 768 * 2);
    ushort* wlp   = (ushort*)alloc(384 * 768 * 2);
    ushort* winb  = (ushort*)alloc((size_t)2 * 1536 * 384 * 2);
    ushort* wob   = (ushort*)alloc((size_t)2 * 384 * 768 * 2);
    ushort* wxpp  = (ushort*)alloc((size_t)2 * 256 * 768 * 2);
    ushort* wdtp  = (ushort*)alloc((size_t)2 * 4 * 768 * 32 * 2);

    cvt_all_k<<<3744, 256, 0, stream>>>(pew, lpw, inw, ow, xpw, dtw,
                                        wpe, wlp, winb, wob, wxpp, wdtp);

    // ---- Stage A ----
    tr_x_k<<<dim3(8, 24, 2), 256, 0, stream>>>(x, xspe);
    gemm_bf<<<dim3(12, 4), 256, 0, stream>>>(xspe, wpe, nullptr, nullptr, t1,
                                             nullptr, nullptr, nullptr,
                                             512, 1536, 768, 0, 0, 0, 0, 0);
    peskip_k<<<1280, 256, 0, stream>>>(t1, pnw, pnb, skip, hbuf);
    gemm_bf<<<dim3(3, 16), 256, 0, stream>>>(hbuf, wlp, lpb, nullptr, xh,
                                             nullptr, nullptr, nullptr,
                                             2048, 384, 768, 0, 0, 0, 0, 0);

    // ---- 2 VSS blocks ----
    for (int blk = 0; blk < 2; ++blk) {
        const ushort* inw_i = winb + (size_t)blk * 1536 * 384;
        const float*  cw_i  = cw + (size_t)blk * 768 * 9;
        const float*  cb_i  = cb + (size_t)blk * 768;
        const ushort* xpw_i = wxpp + (size_t)blk * 256 * 768;
        const ushort* dtw_i = wdtp + (size_t)blk * 4 * 768 * 32;
        const float*  dtb_i = dtbi + (size_t)blk * 4 * 768;
        const float*  al_i  = alog + (size_t)blk * 4 * 768 * 16;
        const float*  ds_i  = ds + (size_t)blk * 4 * 768;
        const float*  onw_i = onw + (size_t)blk * 768;
        const float*  onb_i = onb + (size_t)blk * 768;
        const ushort* ow_i  = wob + (size_t)blk * 384 * 768;

        ln_rows_384<<<512, 256, 0, stream>>>(xh, blw + blk * 384, blb + blk * 384,
                                             hbuf);
        gemm_bf<<<dim3(12, 16), 256, 0, stream>>>(hbuf, inw_i, nullptr, nullptr,
                                                  xz, nullptr, nullptr, nullptr,
                                                  2048, 1536, 384, 0, 0, 0, 0, 0);
        conv_silu_k<<<2048, 256, 0, stream>>>(xz, cw_i, cb_i, xcb);
        gemm_bf<<<dim3(2, 16), 256, 0, stream>>>(xcb, xpw_i, nullptr, nullptr,
                                                 nullptr, nullptr, dblBC, dtrb,
                                                 2048, 256, 768, 0, 0, 0, 0, 2);
        gemm_bf<<<dim3(6, 16, 4), 256, 0, stream>>>(dtrb, dtw_i, dtb_i, nullptr,
                                                    nullptr, dtspb, nullptr, nullptr,
                                                    2048, 768, 32,
                                                    2048 * 32, 768 * 32, 768,
                                                    (long)2048 * 768, 1);
        scan_p1<<<dim3(12, 15, 8), 64, 0, stream>>>(dtspb, dblBC, xcb, al_i,
                                                    Pg, Hg);
        comb_k<<<384, 256, 0, stream>>>(Pg, Hg, H0g);
        scan_p2<<<dim3(12, 16, 8), 64, 0, stream>>>(dtspb, dblBC, xcb, al_i,
                                                    H0g, y4b);
        fuse_out_k<<<512, 256, 0, stream>>>(y4b, xcb, xz, ds_i, onw_i, onb_i,
                                            hbuf);
        gemm_bf<<<dim3(3, 16), 256, 0, stream>>>(hbuf, ow_i, nullptr, xh, xh,
                                                 nullptr, nullptr, nullptr,
                                                 2048, 384, 768, 0, 0, 0, 0, 0);
    }

    tr_out_k<<<dim3(32, 12, 2), 256, 0, stream>>>(xh, out);
}

// Round 6
// 581.760 us; speedup vs baseline: 1.0778x; 1.0778x over previous
//
#include <hip/hip_runtime.h>
#include <math.h>

// Problem constants: B=2, H=W=32 (after expand), L=1024, out_dim=384, Di=768,
// K=4 directions, N=16 state, R=24, depth=2. fp32 in/out; bf16 MFMA GEMMs.

typedef __attribute__((ext_vector_type(8))) short s8v;   // 8 bf16 = 4 VGPRs
typedef __attribute__((ext_vector_type(4))) float f4v;

static __device__ __forceinline__ float sigmoidf_(float x) {
    return 1.f / (1.f + __expf(-x));
}
static __device__ __forceinline__ ushort f2bf(float x) {
    unsigned u = __float_as_uint(x);
    return (ushort)((u + 0x7fff + ((u >> 16) & 1)) >> 16);   // RNE
}
static __device__ __forceinline__ float bf2f(ushort u) {
    return __uint_as_float(((unsigned)u) << 16);
}

// Scan-order <-> spatial-position map. Involution for all k.
static __device__ __forceinline__ int scan_pos(int k, int l) {
    int m = (k & 2) ? (1023 - l) : l;
    return (k & 1) ? (((m & 31) << 5) | (m >> 5)) : m;
}

// ---------------- all weight conversions fp32->bf16 in ONE kernel ----------------
__global__ __launch_bounds__(256) void cvt_all_k(
    const float* __restrict__ pew, const float* __restrict__ lpw,
    const float* __restrict__ inw, const float* __restrict__ ow,
    const float* __restrict__ xpw, const float* __restrict__ dtw,
    ushort* __restrict__ wpe, ushort* __restrict__ wlp,
    ushort* __restrict__ winb, ushort* __restrict__ wob,
    ushort* __restrict__ wxpp, ushort* __restrict__ wdtp) {
    int g = blockIdx.x * 256 + threadIdx.x;
    if (g < 811008) {
        const float* s; ushort* d; int off;
        if (g < 294912)      { s = pew;  d = wpe;  off = g; }
        else if (g < 368640) { s = lpw;  d = wlp;  off = g - 294912; }
        else if (g < 663552) { s = inw;  d = winb; off = g - 368640; }
        else                 { s = ow;   d = wob;  off = g - 663552; }
        float4 v = ((const float4*)s)[off];
        ushort4 o = {f2bf(v.x), f2bf(v.y), f2bf(v.z), f2bf(v.w)};
        ((ushort4*)d)[off] = o;
    } else if (g < 909312) {
        int e = g - 811008;
        int blkb = e / 49152, rem = e % 49152;
        int n = rem / 192, q = rem % 192;
        int k = n >> 6, c = n & 63;
        ushort4 o = {0, 0, 0, 0};
        if (c < 56) {
            float4 v = *(const float4*)(xpw +
                ((size_t)((blkb * 4 + k) * 56 + c)) * 768 + q * 4);
            o = {f2bf(v.x), f2bf(v.y), f2bf(v.z), f2bf(v.w)};
        }
        ((ushort4*)wxpp)[e] = o;
    } else {
        int e = g - 909312;          // 49152 groups
        int rowk = e >> 3, q = e & 7;
        ushort4 o = {0, 0, 0, 0};
        if (q < 6) {
            float4 v = *(const float4*)(dtw + (size_t)rowk * 24 + q * 4);
            o = {f2bf(v.x), f2bf(v.y), f2bf(v.z), f2bf(v.w)};
        }
        ((ushort4*)wdtp)[e] = o;
    }
}

// ---------------- tiled transpose: x (B,768,256) -> (B*256,768) bf16 -------------
__global__ __launch_bounds__(256) void tr_x_k(const float* __restrict__ x,
                                              ushort* __restrict__ o) {
    __shared__ float tile[32][33];
    int b = blockIdx.z, c0 = blockIdx.y * 32, s0 = blockIdx.x * 32;
    int tx = threadIdx.x & 31, ty = threadIdx.x >> 5;
    for (int i = ty; i < 32; i += 8)
        tile[i][tx] = x[((size_t)(b * 768 + c0 + i)) * 256 + s0 + tx];
    __syncthreads();
    for (int i = ty; i < 32; i += 8)
        o[((size_t)(b * 256 + s0 + i)) * 768 + c0 + tx] = f2bf(tile[tx][i]);
}

// ---------------- merged: pe_ln (blocks 0..511) + tr_skip (blocks 512..1279) -----
__global__ __launch_bounds__(256) void peskip_k(const float* __restrict__ t1,
                                                const float* __restrict__ pnw,
                                                const float* __restrict__ pnb,
                                                const float* __restrict__ skip,
                                                ushort* __restrict__ cin) {
    __shared__ float tile[32][33];
    int bx = blockIdx.x;
    if (bx < 512) {
        // pixel-shuffle + LN -> cin cols [0,384), wave per row
        int w = threadIdx.x >> 6, lane = threadIdx.x & 63;
        int row = bx * 4 + w;
        int b = row >> 10, p = row & 1023;
        int r = p >> 5, col = p & 31;
        int i = r >> 1, a = r & 1, j = col >> 1, b2 = col & 1;
        const float* src =
            t1 + ((size_t)(b * 256 + i * 16 + j)) * 1536 + (a * 2 + b2) * 384;
        float v[6], s1 = 0.f, s2 = 0.f;
#pragma unroll
        for (int q = 0; q < 6; ++q) {
            v[q] = src[lane + 64 * q];
            s1 += v[q]; s2 += v[q] * v[q];
        }
#pragma unroll
        for (int m = 1; m < 64; m <<= 1) {
            s1 += __shfl_xor(s1, m); s2 += __shfl_xor(s2, m);
        }
        float mean = s1 * (1.f / 384.f);
        float rstd = rsqrtf(s2 * (1.f / 384.f) - mean * mean + 1e-5f);
        ushort* o = cin + (size_t)row * 768;
#pragma unroll
        for (int q = 0; q < 6; ++q) {
            int c = lane + 64 * q;
            o[c] = f2bf((v[q] - mean) * rstd * pnw[c] + pnb[c]);
        }
    } else {
        // skip (B,384,1024) transpose -> cin cols [384,768)
        int idx = bx - 512;                 // 768 blocks: b (2) x c0 (12) x s0 (32)
        int b = idx / 384, rem = idx % 384;
        int c0 = (rem / 32) * 32, s0 = (rem % 32) * 32;
        int tx = threadIdx.x & 31, ty = threadIdx.x >> 5;
        for (int i = ty; i < 32; i += 8)
            tile[i][tx] = skip[((size_t)(b * 384 + c0 + i)) * 1024 + s0 + tx];
        __syncthreads();
        for (int i = ty; i < 32; i += 8)
            cin[((size_t)(b * 1024 + s0 + i)) * 768 + 384 + c0 + tx] =
                f2bf(tile[tx][i]);
    }
}

// ---------------- tiled transpose: xh (B*1024,384) -> out (B,384,1024) fp32 ------
__global__ __launch_bounds__(256) void tr_out_k(const float* __restrict__ xh,
                                                float* __restrict__ out) {
    __shared__ float tile[32][33];
    int b = blockIdx.z, p0 = blockIdx.x * 32, c0 = blockIdx.y * 32;
    int tx = threadIdx.x & 31, ty = threadIdx.x >> 5;
    for (int i = ty; i < 32; i += 8)
        tile[i][tx] = xh[((size_t)(b * 1024 + p0 + i)) * 384 + c0 + tx];
    __syncthreads();
    for (int i = ty; i < 32; i += 8)
        out[((size_t)(b * 384 + c0 + i)) * 1024 + p0 + tx] = tile[tx][i];
}

// ---------------- bf16 NT MFMA GEMM, z-batched, 3 epilogue modes -----------------
// SOFTWARE-PIPELINED: double-buffered LDS; global loads for tile t+1 issued
// before the MFMAs of tile t, awaited (vmcnt) only at the LDS write after the
// MFMAs. One barrier per K-iteration. This removes the per-iteration full
// memory-latency drain that made the 48-block dispatches latency-bound (R5:
// 44 us @ 1% MfmaUtil).
// mode 0: Cf = acc (+bias)(+res)  fp32
// mode 1: Cb = bf16(softplus(acc + bias))          [z-batched]
// mode 2: xproj scatter: dtrb bf16 (c<32, zero-pad 24..31), dblBC fp32 scan-order
__global__ __launch_bounds__(256) void gemm_bf(const ushort* __restrict__ A,
                                               const ushort* __restrict__ B,
                                               const float* __restrict__ bias,
                                               const float* __restrict__ res,
                                               float* __restrict__ Cf,
                                               ushort* __restrict__ Cb,
                                               float* __restrict__ dblBC,
                                               ushort* __restrict__ dtrb,
                                               int M, int N, int K,
                                               long sAz, long sBz, long sBiz,
                                               long sCz, int mode) {
    __shared__ ushort Als[2][128][40];   // 80 B rows: 20-bank stride, worst 2-way
    __shared__ ushort Bls[2][128][40];
    A += (size_t)blockIdx.z * sAz;
    B += (size_t)blockIdx.z * sBz;
    if (Cf) Cf += (size_t)blockIdx.z * sCz;
    if (Cb) Cb += (size_t)blockIdx.z * sCz;
    if (bias) bias += (size_t)blockIdx.z * sBiz;
    int t = threadIdx.x;
    int bm = blockIdx.y * 128, bn = blockIdx.x * 128;
    int lane = t & 63, w = t >> 6;
    int wm = (w & 1) * 64, wn = (w >> 1) * 64;
    int r16 = lane & 15, quad = lane >> 4;
    int srow = t >> 1, shalf = t & 1;
    f4v acc[4][4] = {};
    const ushort* Ag = A + (size_t)(bm + srow) * K + shalf * 16;
    const ushort* Bg = B + (size_t)(bn + srow) * K + shalf * 16;
    int nt = K >> 5;
    // prologue: tile 0 -> LDS[0]
    uint4 a0 = *(const uint4*)(Ag);
    uint4 a1 = *(const uint4*)(Ag + 8);
    uint4 b0 = *(const uint4*)(Bg);
    uint4 b1 = *(const uint4*)(Bg + 8);
    *(uint4*)&Als[0][srow][shalf * 16] = a0;
    *(uint4*)&Als[0][srow][shalf * 16 + 8] = a1;
    *(uint4*)&Bls[0][srow][shalf * 16] = b0;
    *(uint4*)&Bls[0][srow][shalf * 16 + 8] = b1;
    for (int it = 0; it < nt; ++it) {
        int buf = it & 1;
        __syncthreads();                  // LDS[buf] ready; prev reads of buf^1 done
        if (it + 1 < nt) {                // issue next tile's loads (awaited below)
            int k0 = (it + 1) << 5;
            a0 = *(const uint4*)(Ag + k0);
            a1 = *(const uint4*)(Ag + k0 + 8);
            b0 = *(const uint4*)(Bg + k0);
            b1 = *(const uint4*)(Bg + k0 + 8);
        }
        s8v af[4], bfr[4];
#pragma unroll
        for (int i = 0; i < 4; ++i) {
            af[i]  = *(const s8v*)&Als[buf][wm + i * 16 + r16][quad * 8];
            bfr[i] = *(const s8v*)&Bls[buf][wn + i * 16 + r16][quad * 8];
        }
#pragma unroll
        for (int i = 0; i < 4; ++i)
#pragma unroll
            for (int j = 0; j < 4; ++j)
                acc[i][j] = __builtin_amdgcn_mfma_f32_16x16x32_bf16(
                    af[i], bfr[j], acc[i][j], 0, 0, 0);
        if (it + 1 < nt) {                // vmcnt wait lands here, after MFMAs
            *(uint4*)&Als[buf ^ 1][srow][shalf * 16] = a0;
            *(uint4*)&Als[buf ^ 1][srow][shalf * 16 + 8] = a1;
            *(uint4*)&Bls[buf ^ 1][srow][shalf * 16] = b0;
            *(uint4*)&Bls[buf ^ 1][srow][shalf * 16 + 8] = b1;
        }
    }
    // D mapping: col=lane&15, row=quad*4+reg (m89-verified)
#pragma unroll
    for (int i = 0; i < 4; ++i) {
        int row0 = bm + wm + i * 16 + quad * 4;
#pragma unroll
        for (int j = 0; j < 4; ++j) {
            int col = bn + wn + j * 16 + r16;
            float bv = bias ? bias[col] : 0.f;
#pragma unroll
            for (int r = 0; r < 4; ++r) {
                int row = row0 + r;
                float v = acc[i][j][r] + bv;
                if (mode == 0) {
                    if (res) v += res[(size_t)row * N + col];
                    Cf[(size_t)row * N + col] = v;
                } else if (mode == 1) {
                    v = (v > 20.f) ? v : log1pf(__expf(v));
                    Cb[(size_t)row * N + col] = f2bf(v);
                } else {
                    int k = col >> 6, c = col & 63;
                    int b = row >> 10, p = row & 1023;
                    if (c < 32)
                        dtrb[((size_t)k * 2048 + row) * 32 + c] =
                            f2bf((c < 24) ? v : 0.f);
                    if (c >= 24 && c < 56) {
                        int l = scan_pos(k, p);
                        dblBC[(((size_t)(b * 4 + k)) * 1024 + l) * 32 + (c - 24)] = v;
                    }
                }
            }
        }
    }
}

// ---------------- row LayerNorm over 384 cols -> bf16 (wave/row) ----------------
__global__ __launch_bounds__(256) void ln_rows_384(const float* __restrict__ in,
                                                   const float* __restrict__ wgt,
                                                   const float* __restrict__ bb,
                                                   ushort* __restrict__ out) {
    int w = threadIdx.x >> 6, lane = threadIdx.x & 63;
    int row = blockIdx.x * 4 + w;      // grid 512
    const float* x = in + (size_t)row * 384;
    float v[6], s1 = 0.f, s2 = 0.f;
#pragma unroll
    for (int q = 0; q < 6; ++q) {
        v[q] = x[lane + 64 * q];
        s1 += v[q]; s2 += v[q] * v[q];
    }
#pragma unroll
    for (int m = 1; m < 64; m <<= 1) {
        s1 += __shfl_xor(s1, m); s2 += __shfl_xor(s2, m);
    }
    float mean = s1 * (1.f / 384.f);
    float rstd = rsqrtf(s2 * (1.f / 384.f) - mean * mean + 1e-5f);
#pragma unroll
    for (int q = 0; q < 6; ++q) {
        int c = lane + 64 * q;
        out[(size_t)row * 384 + c] = f2bf((v[q] - mean) * rstd * wgt[c] + bb[c]);
    }
}

// ---------------- depthwise 3x3 conv + bias + SiLU -> xcb bf16 only --------------
__global__ __launch_bounds__(256) void conv_silu_k(const float* __restrict__ xz,
                                                   const float* __restrict__ cw,
                                                   const float* __restrict__ cb,
                                                   ushort* __restrict__ xcb) {
    int row = blockIdx.x;
    int b = row >> 10, p = row & 1023;
    int r = p >> 5, col = p & 31;
    for (int d = threadIdx.x; d < 768; d += 256) {
        float acc = cb[d];
#pragma unroll
        for (int dy = 0; dy < 3; ++dy) {
            int rr = r + dy - 1;
            if ((unsigned)rr > 31u) continue;
#pragma unroll
            for (int dx = 0; dx < 3; ++dx) {
                int cc = col + dx - 1;
                if ((unsigned)cc > 31u) continue;
                acc += cw[d * 9 + dy * 3 + dx] *
                       xz[((size_t)(b * 1024 + rr * 32 + cc)) * 1536 + d];
            }
        }
        float o = acc * sigmoidf_(acc);
        xcb[(size_t)row * 768 + d] = f2bf(o);
    }
}

// ======== selective scan: p1 (chunk P,H) -> comb (prefix h0) -> p2 (emit) ========
// dtspb bf16 [k][b*1024+p][768]; xcb bf16 [b*1024+p][768]; dblBC fp32 scan-order.
// Pg/Hg/H0g layout: [(kb*16+ch)*12288 + d*16 + n].

__global__ __launch_bounds__(64) void scan_p1(const ushort* __restrict__ dtspb,
                                              const float* __restrict__ dblBC,
                                              const ushort* __restrict__ xcb,
                                              const float* __restrict__ alog,
                                              float* __restrict__ Pg,
                                              float* __restrict__ Hg) {
    __shared__ float sB[32][16];
    int lane = threadIdx.x;
    int d0 = blockIdx.x * 64, ch = blockIdx.y, kb = blockIdx.z;
    int k = kb & 3, b = kb >> 2;
    int d = d0 + lane;
    float A2[16];
    {
        const float4* ap = (const float4*)(alog + ((size_t)(k * 768 + d)) * 16);
#pragma unroll
        for (int q = 0; q < 4; ++q) {
            float4 v = ap[q];
            A2[4 * q + 0] = -__expf(v.x) * 1.44269504f;
            A2[4 * q + 1] = -__expf(v.y) * 1.44269504f;
            A2[4 * q + 2] = -__expf(v.z) * 1.44269504f;
            A2[4 * q + 3] = -__expf(v.w) * 1.44269504f;
        }
    }
    const ushort* dts = dtspb + ((size_t)(k * 2048 + b * 1024)) * 768 + d;
    const ushort* xub = xcb + (size_t)b * 786432 + d;
    const float* bcp = dblBC + (size_t)kb * 1024 * 32;
    int l0 = ch * 64;
    float h[16], P[16];
#pragma unroll
    for (int n = 0; n < 16; ++n) { h[n] = 0.f; P[n] = 1.f; }
    int bi = lane >> 4, bn_ = lane & 15;
#pragma unroll 1
    for (int w = 0; w < 2; ++w) {
        int lw = l0 + w * 32;
        float rdt[32], ru[32], rB[8];
#pragma unroll
        for (int i = 0; i < 32; ++i) {
            int p = scan_pos(k, lw + i);
            rdt[i] = bf2f(dts[(size_t)p * 768]);
            ru[i] = bf2f(xub[(size_t)p * 768]);
        }
#pragma unroll
        for (int j = 0; j < 8; ++j)
            rB[j] = bcp[(size_t)(lw + bi + 4 * j) * 32 + bn_];
        __syncthreads();
#pragma unroll
        for (int j = 0; j < 8; ++j) sB[bi + 4 * j][bn_] = rB[j];
        __syncthreads();
#pragma unroll 4
        for (int i = 0; i < 32; ++i) {
            float dtv = rdt[i], dtu = dtv * ru[i];
            const float4* B4 = (const float4*)&sB[i][0];
            float4 q0 = B4[0], q1 = B4[1], q2 = B4[2], q3 = B4[3];
            float Bv[16] = {q0.x, q0.y, q0.z, q0.w, q1.x, q1.y, q1.z, q1.w,
                            q2.x, q2.y, q2.z, q2.w, q3.x, q3.y, q3.z, q3.w};
#pragma unroll
            for (int n = 0; n < 16; ++n) {
                float a = __builtin_amdgcn_exp2f(dtv * A2[n]);
                P[n] *= a;
                h[n] = a * h[n] + dtu * Bv[n];
            }
        }
    }
    float* pp = Pg + ((size_t)(kb * 16 + ch)) * 12288 + d * 16;
    float* hp = Hg + ((size_t)(kb * 16 + ch)) * 12288 + d * 16;
#pragma unroll
    for (int q = 0; q < 4; ++q) {
        float4 pv = {P[4 * q], P[4 * q + 1], P[4 * q + 2], P[4 * q + 3]};
        float4 hv = {h[4 * q], h[4 * q + 1], h[4 * q + 2], h[4 * q + 3]};
        *(float4*)(pp + 4 * q) = pv;
        *(float4*)(hp + 4 * q) = hv;
    }
}

// prefix fold: h0[ch] for all chains. grid 384 x 256 threads, fully unrolled.
__global__ __launch_bounds__(256) void comb_k(const float* __restrict__ Pg,
                                              const float* __restrict__ Hg,
                                              float* __restrict__ H0g) {
    int t = blockIdx.x * 256 + threadIdx.x;   // 98304 = 8 kb * 12288 (d*16+n)
    int kb = t / 12288, dn = t % 12288;
    size_t base = (size_t)kb * 16 * 12288 + dn;
    float pv[15], hv[15];
#pragma unroll
    for (int ch = 0; ch < 15; ++ch) {
        pv[ch] = Pg[base + (size_t)ch * 12288];
        hv[ch] = Hg[base + (size_t)ch * 12288];
    }
    float h = 0.f;
    H0g[base] = 0.f;
#pragma unroll
    for (int ch = 0; ch < 15; ++ch) {
        h = pv[ch] * h + hv[ch];
        H0g[base + (size_t)(ch + 1) * 12288] = h;
    }
}

__global__ __launch_bounds__(64) void scan_p2(const ushort* __restrict__ dtspb,
                                              const float* __restrict__ dblBC,
                                              const ushort* __restrict__ xcb,
                                              const float* __restrict__ alog,
                                              const float* __restrict__ H0g,
                                              ushort* __restrict__ y4b) {
    __shared__ float sB[32][16];
    __shared__ float sC[32][16];
    int lane = threadIdx.x;
    int d0 = blockIdx.x * 64, ch = blockIdx.y, kb = blockIdx.z;
    int k = kb & 3, b = kb >> 2;
    int d = d0 + lane;
    float A2[16];
    {
        const float4* ap = (const float4*)(alog + ((size_t)(k * 768 + d)) * 16);
#pragma unroll
        for (int q = 0; q < 4; ++q) {
            float4 v = ap[q];
            A2[4 * q + 0] = -__expf(v.x) * 1.44269504f;
            A2[4 * q + 1] = -__expf(v.y) * 1.44269504f;
            A2[4 * q + 2] = -__expf(v.z) * 1.44269504f;
            A2[4 * q + 3] = -__expf(v.w) * 1.44269504f;
        }
    }
    float h[16];
    {
        const float4* h0p =
            (const float4*)(H0g + ((size_t)(kb * 16 + ch)) * 12288 + d * 16);
#pragma unroll
        for (int q = 0; q < 4; ++q) {
            float4 hv = h0p[q];
            h[4 * q + 0] = hv.x; h[4 * q + 1] = hv.y;
            h[4 * q + 2] = hv.z; h[4 * q + 3] = hv.w;
        }
    }
    const ushort* dts = dtspb + ((size_t)(k * 2048 + b * 1024)) * 768 + d;
    const ushort* xub = xcb + (size_t)b * 786432 + d;
    const float* bcp = dblBC + (size_t)kb * 1024 * 32;
    ushort* yp = y4b + (size_t)kb * 786432 + d;
    int l0 = ch * 64;
    int bi = lane >> 4, bn_ = lane & 15;
#pragma unroll 1
    for (int w = 0; w < 2; ++w) {
        int lw = l0 + w * 32;
        float rdt[32], ru[32], rB[8], rC[8];
#pragma unroll
        for (int i = 0; i < 32; ++i) {
            int p = scan_pos(k, lw + i);
            rdt[i] = bf2f(dts[(size_t)p * 768]);
            ru[i] = bf2f(xub[(size_t)p * 768]);
        }
#pragma unroll
        for (int j = 0; j < 8; ++j) {
            rB[j] = bcp[(size_t)(lw + bi + 4 * j) * 32 + bn_];
            rC[j] = bcp[(size_t)(lw + bi + 4 * j) * 32 + 16 + bn_];
        }
        __syncthreads();
#pragma unroll
        for (int j = 0; j < 8; ++j) {
            sB[bi + 4 * j][bn_] = rB[j];
            sC[bi + 4 * j][bn_] = rC[j];
        }
        __syncthreads();
#pragma unroll 4
        for (int i = 0; i < 32; ++i) {
            float dtv = rdt[i], dtu = dtv * ru[i];
            const float4* B4 = (const float4*)&sB[i][0];
            const float4* C4 = (const float4*)&sC[i][0];
            float4 q0 = B4[0], q1 = B4[1], q2 = B4[2], q3 = B4[3];
            float Bv[16] = {q0.x, q0.y, q0.z, q0.w, q1.x, q1.y, q1.z, q1.w,
                            q2.x, q2.y, q2.z, q2.w, q3.x, q3.y, q3.z, q3.w};
            float4 c0 = C4[0], c1 = C4[1], c2 = C4[2], c3 = C4[3];
            float Cv[16] = {c0.x, c0.y, c0.z, c0.w, c1.x, c1.y, c1.z, c1.w,
                            c2.x, c2.y, c2.z, c2.w, c3.x, c3.y, c3.z, c3.w};
            float y = 0.f;
#pragma unroll
            for (int n = 0; n < 16; ++n) {
                float a = __builtin_amdgcn_exp2f(dtv * A2[n]);
                h[n] = a * h[n] + dtu * Bv[n];
                y += h[n] * Cv[n];
            }
            int p = scan_pos(k, lw + i);
            yp[(size_t)p * 768] = f2bf(y);
        }
    }
}

// ---------------- sum 4 dirs + D*u, out-LN, * silu(z) -> g bf16 (wave/row) -------
__global__ __launch_bounds__(256) void fuse_out_k(const ushort* __restrict__ y4b,
                                                  const ushort* __restrict__ xcb,
                                                  const float* __restrict__ xz,
                                                  const float* __restrict__ ds,
                                                  const float* __restrict__ onw,
                                                  const float* __restrict__ onb,
                                                  ushort* __restrict__ g) {
    int w = threadIdx.x >> 6, lane = threadIdx.x & 63;
    int row = blockIdx.x * 4 + w;      // grid 512
    int b = row >> 10, p = row & 1023;
    float v[12], s1 = 0.f, s2 = 0.f;
#pragma unroll
    for (int q = 0; q < 12; ++q) {
        int d = lane + 64 * q;
        float u = bf2f(xcb[(size_t)row * 768 + d]);
        float dsum = ds[d] + ds[768 + d] + ds[1536 + d] + ds[2304 + d];
        float val = dsum * u;
#pragma unroll
        for (int k = 0; k < 4; ++k)
            val += bf2f(y4b[(((size_t)(b * 4 + k)) * 1024 + p) * 768 + d]);
        v[q] = val; s1 += val; s2 += val * val;
    }
#pragma unroll
    for (int m = 1; m < 64; m <<= 1) {
        s1 += __shfl_xor(s1, m); s2 += __shfl_xor(s2, m);
    }
    float mean = s1 * (1.f / 768.f);
    float rstd = rsqrtf(s2 * (1.f / 768.f) - mean * mean + 1e-5f);
#pragma unroll
    for (int q = 0; q < 12; ++q) {
        int d = lane + 64 * q;
        float zz = xz[(size_t)row * 1536 + 768 + d];
        float sil = zz * sigmoidf_(zz);
        g[(size_t)row * 768 + d] = f2bf(((v[q] - mean) * rstd * onw[d] + onb[d]) * sil);
    }
}

extern "C" void kernel_launch(void* const* d_in, const int* in_sizes, int n_in,
                              void* d_out, int out_size, void* d_ws, size_t ws_size,
                              hipStream_t stream) {
    const float* x    = (const float*)d_in[0];
    const float* skip = (const float*)d_in[1];
    const float* pew  = (const float*)d_in[2];
    const float* pnw  = (const float*)d_in[3];
    const float* pnb  = (const float*)d_in[4];
    const float* lpw  = (const float*)d_in[5];
    const float* lpb  = (const float*)d_in[6];
    const float* blw  = (const float*)d_in[7];
    const float* blb  = (const float*)d_in[8];
    const float* inw  = (const float*)d_in[9];
    const float* cw   = (const float*)d_in[10];
    const float* cb   = (const float*)d_in[11];
    const float* xpw  = (const float*)d_in[12];
    const float* dtw  = (const float*)d_in[13];
    const float* dtbi = (const float*)d_in[14];
    const float* alog = (const float*)d_in[15];
    const float* ds   = (const float*)d_in[16];
    const float* onw  = (const float*)d_in[17];
    const float* onb  = (const float*)d_in[18];
    const float* ow   = (const float*)d_in[19];
    float* out = (float*)d_out;

    char* base = (char*)d_ws;
    auto alloc = [&](size_t bytes) -> char* {
        char* p = base;
        base += (bytes + 255) & ~(size_t)255;
        return p;
    };
    float*  xh    = (float*)alloc(2048 * 384 * 4);
    ushort* hbuf  = (ushort*)alloc(2048 * 768 * 2);
    float*  xz    = (float*)alloc((size_t)2048 * 1536 * 4);
    ushort* xcb   = (ushort*)alloc(2048 * 768 * 2);
    float*  dblBC = (float*)alloc(8192 * 32 * 4);
    ushort* dtrb  = (ushort*)alloc((size_t)4 * 2048 * 32 * 2);
    ushort* dtspb = (ushort*)alloc((size_t)4 * 2048 * 768 * 2);
    ushort* y4b   = (ushort*)alloc((size_t)8192 * 768 * 2);
    float*  Pg    = (float*)alloc((size_t)8 * 16 * 12288 * 4);
    float*  Hg    = (float*)alloc((size_t)8 * 16 * 12288 * 4);
    float*  H0g   = (float*)alloc((size_t)8 * 16 * 12288 * 4);
    ushort* xspe  = (ushort*)alloc(512 * 768 * 2);
    float*  t1    = (float*)alloc(512 * 1536 * 4);
    ushort* wpe   = (ushort*)alloc((size_t)1536 * 768 * 2);
    ushort* wlp   = (ushort*)alloc(384 * 768 * 2);
    ushort* winb  = (ushort*)alloc((size_t)2 * 1536 * 384 * 2);
    ushort* wob   = (ushort*)alloc((size_t)2 * 384 * 768 * 2);
    ushort* wxpp  = (ushort*)alloc((size_t)2 * 256 * 768 * 2);
    ushort* wdtp  = (ushort*)alloc((size_t)2 * 4 * 768 * 32 * 2);

    cvt_all_k<<<3744, 256, 0, stream>>>(pew, lpw, inw, ow, xpw, dtw,
                                        wpe, wlp, winb, wob, wxpp, wdtp);

    // ---- Stage A ----
    tr_x_k<<<dim3(8, 24, 2), 256, 0, stream>>>(x, xspe);
    gemm_bf<<<dim3(12, 4), 256, 0, stream>>>(xspe, wpe, nullptr, nullptr, t1,
                                             nullptr, nullptr, nullptr,
                                             512, 1536, 768, 0, 0, 0, 0, 0);
    peskip_k<<<1280, 256, 0, stream>>>(t1, pnw, pnb, skip, hbuf);
    gemm_bf<<<dim3(3, 16), 256, 0, stream>>>(hbuf, wlp, lpb, nullptr, xh,
                                             nullptr, nullptr, nullptr,
                                             2048, 384, 768, 0, 0, 0, 0, 0);

    // ---- 2 VSS blocks ----
    for (int blk = 0; blk < 2; ++blk) {
        const ushort* inw_i = winb + (size_t)blk * 1536 * 384;
        const float*  cw_i  = cw + (size_t)blk * 768 * 9;
        const float*  cb_i  = cb + (size_t)blk * 768;
        const ushort* xpw_i = wxpp + (size_t)blk * 256 * 768;
        const ushort* dtw_i = wdtp + (size_t)blk * 4 * 768 * 32;
        const float*  dtb_i = dtbi + (size_t)blk * 4 * 768;
        const float*  al_i  = alog + (size_t)blk * 4 * 768 * 16;
        const float*  ds_i  = ds + (size_t)blk * 4 * 768;
        const float*  onw_i = onw + (size_t)blk * 768;
        const float*  onb_i = onb + (size_t)blk * 768;
        const ushort* ow_i  = wob + (size_t)blk * 384 * 768;

        ln_rows_384<<<512, 256, 0, stream>>>(xh, blw + blk * 384, blb + blk * 384,
                                             hbuf);
        gemm_bf<<<dim3(12, 16), 256, 0, stream>>>(hbuf, inw_i, nullptr, nullptr,
                                                  xz, nullptr, nullptr, nullptr,
                                                  2048, 1536, 384, 0, 0, 0, 0, 0);
        conv_silu_k<<<2048, 256, 0, stream>>>(xz, cw_i, cb_i, xcb);
        gemm_bf<<<dim3(2, 16), 256, 0, stream>>>(xcb, xpw_i, nullptr, nullptr,
                                                 nullptr, nullptr, dblBC, dtrb,
                                                 2048, 256, 768, 0, 0, 0, 0, 2);
        gemm_bf<<<dim3(6, 16, 4), 256, 0, stream>>>(dtrb, dtw_i, dtb_i, nullptr,
                                                    nullptr, dtspb, nullptr, nullptr,
                                                    2048, 768, 32,
                                                    2048 * 32, 768 * 32, 768,
                                                    (long)2048 * 768, 1);
        scan_p1<<<dim3(12, 15, 8), 64, 0, stream>>>(dtspb, dblBC, xcb, al_i,
                                                    Pg, Hg);
        comb_k<<<384, 256, 0, stream>>>(Pg, Hg, H0g);
        scan_p2<<<dim3(12, 16, 8), 64, 0, stream>>>(dtspb, dblBC, xcb, al_i,
                                                    H0g, y4b);
        fuse_out_k<<<512, 256, 0, stream>>>(y4b, xcb, xz, ds_i, onw_i, onb_i,
                                            hbuf);
        gemm_bf<<<dim3(3, 16), 256, 0, stream>>>(hbuf, ow_i, nullptr, xh, xh,
                                                 nullptr, nullptr, nullptr,
                                                 2048, 384, 768, 0, 0, 0, 0, 0);
    }

    tr_out_k<<<dim3(32, 12, 2), 256, 0, stream>>>(xh, out);
}